// Round 6
// baseline (277.742 us; speedup 1.0000x reference)
//
#include <hip/hip_runtime.h>
#include <float.h>
#include <stdint.h>

#define DIM      512
#define NCLS     21
#define MARGIN_V 5.0f
#define NWAVES   4                 // waves per block, each owns 64 whole rows
#define ROWS_PB  (NWAVES * 64)     // 256 rows per block
#define DC       16                // floats staged per stage per row
#define NSTAGE   (DIM / DC)        // 32
#define BUF4     (ROWS_PB * DC / 4)  // 1024 float4 per buffer (16 KB)

typedef __attribute__((address_space(3))) uint32_t       lds_u32_t;
typedef const __attribute__((address_space(1))) uint32_t glb_u32_t;

// Kernel 1: halfc2[c] = 0.5*||centers[c]||^2 -> d_ws ; block 0 also zeroes d_out
__global__ __launch_bounds__(64)
void center_norm_kernel(const float* __restrict__ centers,
                        float* __restrict__ halfc2,
                        float* __restrict__ out) {
    const int c = blockIdx.x;
    const int t = threadIdx.x;
    if (c == 0 && t == 0) out[0] = 0.f;     // same-stream order replaces memset
    float s = 0.f;
#pragma unroll
    for (int i = 0; i < DIM / 64; ++i) {
        float v = centers[c * DIM + i * 64 + t];
        s = fmaf(v, v, s);
    }
#pragma unroll
    for (int off = 32; off > 0; off >>= 1)
        s += __shfl_down(s, off, 64);
    if (t == 0) halfc2[c] = 0.5f * s;
}

// Kernel 2: 4 waves x 64 rows, ALL waves sweep the same depth window so center
// addresses are WORKGROUP-uniform -> compiler scalarizes them to s_load (SGPR
// operands, lgkmcnt). Round 5's wave-varying slices forced per-lane VMEM
// center loads sharing the vmcnt FIFO with the LDS-DMA -> pipeline defeated.
// Here the K-loop's only vmcnt traffic is the double-buffered DMA.
__global__ __launch_bounds__(256)
void tcl_main_kernel(const float* __restrict__ feat,
                     const float* __restrict__ centers,
                     const int* __restrict__ labels,
                     const float* __restrict__ halfc2,
                     float* __restrict__ out) {
    // 2 buffers x (256 rows x 16 floats) = 32 KB
    __shared__ float smem[2 * ROWS_PB * DC];

    const int tid  = threadIdx.x;
    const int w    = tid >> 6;      // wave id 0..3 -> owns rows w*64..w*64+63
    const int t    = tid & 63;      // lane id
    const int row0 = blockIdx.x * ROWS_PB;
    const int myrow = row0 + w * 64 + t;     // this lane's row

    const int lab = labels[myrow];           // load early, epilogue-only use

    float4* bufs[2];
    bufs[0] = reinterpret_cast<float4*>(smem);
    bufs[1] = reinterpret_cast<float4*>(smem) + BUF4;
    // wave's 64-row section within each buffer (64 rows x 4 float4)
    const int wsec = w * 64 * (DC / 4);

    const float4* fb = reinterpret_cast<const float4*>(feat)
                     + (size_t)(row0 + w * 64) * (DIM / 4);

    // DMA issue k deposits at section slot k*64+t; slot holds row r=slot>>2,
    // col j4=(slot&3)^(r&3) (XOR swizzle, DMA-compatible: wave-uniform base +
    // lane*16). 4-lane groups cover one row's 64 B permuted -> coalesced.
    const float4* gp[4];
#pragma unroll
    for (int k = 0; k < 4; ++k) {
        int slot = k * 64 + t;
        int r    = slot >> 2;
        int j4   = (slot & 3) ^ (r & 3);
        gp[k] = fb + (size_t)r * (DIM / 4) + j4;
    }

    float acc[NCLS];
#pragma unroll
    for (int c = 0; c < NCLS; ++c) acc[c] = 0.f;

    const int xr = t & 3;           // readback xor key for lane t (row t)

    // prologue: stage 0 -> buf0
#pragma unroll
    for (int k = 0; k < 4; ++k)
        __builtin_amdgcn_global_load_lds((glb_u32_t*)gp[k],
                                         (lds_u32_t*)(bufs[0] + wsec + k * 64),
                                         16, 0, 0);

#pragma unroll 1
    for (int s = 0; s < NSTAGE; ++s) {
        __syncthreads();            // drains own vmcnt(0): DMA(s) complete
                                    // (issued one full compute phase ago)
        if (s + 1 < NSTAGE) {
            float4* nb = bufs[(s + 1) & 1] + wsec;
#pragma unroll
            for (int k = 0; k < 4; ++k)
                __builtin_amdgcn_global_load_lds((glb_u32_t*)(gp[k] + (s + 1) * (DC / 4)),
                                                 (lds_u32_t*)(nb + k * 64),
                                                 16, 0, 0);
        }

        // row t's 16 floats for this window (4 ds_read_b128)
        const float4* tb = bufs[s & 1] + wsec;
        float4 f0 = tb[t * 4 + (0 ^ xr)];
        float4 f1 = tb[t * 4 + (1 ^ xr)];
        float4 f2 = tb[t * 4 + (2 ^ xr)];
        float4 f3 = tb[t * 4 + (3 ^ xr)];

        // centers: workgroup-uniform address -> s_load; SGPR operand FMAs
        const float* cp0 = centers + s * DC;
#pragma unroll
        for (int c = 0; c < NCLS; ++c) {
            const float* cp = cp0 + c * DIM;
            acc[c] = fmaf(f0.x, cp[0],
                      fmaf(f0.y, cp[1],
                       fmaf(f0.z, cp[2],
                        fmaf(f0.w, cp[3],
                         fmaf(f1.x, cp[4],
                          fmaf(f1.y, cp[5],
                           fmaf(f1.z, cp[6],
                            fmaf(f1.w, cp[7],
                             fmaf(f2.x, cp[8],
                              fmaf(f2.y, cp[9],
                               fmaf(f2.z, cp[10],
                                fmaf(f2.w, cp[11],
                                 fmaf(f3.x, cp[12],
                                  fmaf(f3.y, cp[13],
                                   fmaf(f3.z, cp[14],
                                    fmaf(f3.w, cp[15], acc[c]))))))))))))))));
        }
    }

    // per-wave epilogue: each wave has complete dots for its 64 rows
    float pos = 0.f, neg = FLT_MAX;
#pragma unroll
    for (int c = 0; c < NCLS; ++c) {
        float e = halfc2[c] - acc[c];        // ||f||^2 cancels in pos-neg
        pos = (c == lab) ? e : pos;
        neg = (c == lab) ? neg : fminf(neg, e);
    }
    float vv = fmaxf(pos + MARGIN_V - neg, 0.f);
#pragma unroll
    for (int off = 32; off > 0; off >>= 1)
        vv += __shfl_down(vv, off, 64);
    if (t == 0) atomicAdd(out, vv * (1.0f / 65536.f));
}

extern "C" void kernel_launch(void* const* d_in, const int* in_sizes, int n_in,
                              void* d_out, int out_size, void* d_ws, size_t ws_size,
                              hipStream_t stream) {
    const float* feat    = (const float*)d_in[0];   // (65536, 512) fp32
    const float* centers = (const float*)d_in[1];   // (21, 512) fp32
    const int*   labels  = (const int*)d_in[2];     // (65536,)
    float* out    = (float*)d_out;                  // scalar loss
    float* halfc2 = (float*)d_ws;                   // 21 floats scratch

    center_norm_kernel<<<NCLS, 64, 0, stream>>>(centers, halfc2, out);

    const int nblocks = 65536 / ROWS_PB;            // 256 blocks x 256 threads
    tcl_main_kernel<<<nblocks, 256, 0, stream>>>(feat, centers, labels, halfc2, out);
}